// Round 8
// baseline (454.178 us; speedup 1.0000x reference)
//
#include <hip/hip_runtime.h>
#include <hip/hip_bf16.h>
#include <math.h>

#define BB 8
#define CC 64
#define NN 500
#define TT 12
#define HH 4
#define FF 64
#define CT (CC*TT)      // 768
#define HF (HH*FF)      // 256
#define NBT (HH*TT)     // 48
#define NBHT (BB*NBT)   // 384
#define NROWS (BB*HH*TT*NN)  // 192000
#define NNODE (BB*NN)   // 4000

typedef unsigned short ushort_t;
typedef unsigned int uint_t;
typedef __attribute__((ext_vector_type(8))) short short8;
typedef __attribute__((ext_vector_type(4))) float floatx4;

static __device__ __forceinline__ ushort_t f2bf(float v) {
    __hip_bfloat16 h = __float2bfloat16(v);
    ushort_t u;
    __builtin_memcpy(&u, &h, 2);
    return u;
}

// pack two f32 -> packed bf16 (lo = a, hi = b), RNE (hw v_cvt_pk on gfx950)
static __device__ __forceinline__ uint_t pkbf(float a, float b) {
    __hip_bfloat162 h = __float22bfloat162_rn(make_float2(a, b));
    uint_t u;
    __builtin_memcpy(&u, &h, 4);
    return u;
}

// ---------------------------------------------------------------------------
// K01: setup.  Blocks [0,1024): dense f32 mask[512][512] (1.0/0.0, padded 0).
// Blocks [1024,1138): p1/p2 folds, WmT transpose, WgB = bf16(Wg).
// ---------------------------------------------------------------------------
__global__ __launch_bounds__(256) void k01_setup(const float* __restrict__ adj,
                                                 const float* __restrict__ W,
                                                 const float* __restrict__ a1,
                                                 const float* __restrict__ a2,
                                                 const float* __restrict__ Wm,
                                                 const float* __restrict__ Wg,
                                                 float* __restrict__ maskF,
                                                 float* __restrict__ p1,
                                                 float* __restrict__ p2,
                                                 float* __restrict__ WmT,
                                                 ushort_t* __restrict__ WgB) {
    int blk = blockIdx.x;
    if (blk < 1024) {
        int idx = blk * 256 + threadIdx.x;   // < 512*512
        int n = idx >> 9, m = idx & 511;
        float v = 0.f;
        if (n < NN && m < NN)
            v = (adj[n*NN + m] > 0.f || m == n) ? 1.f : 0.f;
        maskF[idx] = v;
        return;
    }
    int idx = (blk - 1024) * 256 + threadIdx.x;
    if (idx < HH*CC) {
        int h = idx / CC, c = idx % CC;
        float s1 = 0.f, s2 = 0.f;
        for (int f = 0; f < FF; ++f) {
            float w = W[(h*CC + c)*FF + f];
            s1 += w * a1[h*FF + f];
            s2 += w * a2[h*FF + f];
        }
        p1[idx] = s1; p2[idx] = s2;
    }
    int j = idx - HH*CC;
    if (j >= 0 && j < 3*CC*CC) {
        int c = j >> 6, o = j & 63;
        WmT[j] = Wm[o*(3*CC) + c];
    }
    int j2 = idx - (HH*CC + 3*CC*CC);
    if (j2 >= 0 && j2 < FF*HF) {
        WgB[j2] = f2bf(Wg[j2]);
    }
}

// ---------------------------------------------------------------------------
// K6: transpose x [B,C,N,T] -> xT [(b*N+n)*768 + c*12 + t] (node-major).
// ---------------------------------------------------------------------------
__global__ __launch_bounds__(256) void k6_xt(const float* __restrict__ x,
                                             float* __restrict__ xT) {
    __shared__ float tile[16*776];   // 49664 B
    int b  = blockIdx.x >> 5;
    int n0 = (blockIdx.x & 31) * 16;
    for (int idx = threadIdx.x; idx < CC*16*TT; idx += 256) {
        int c   = idx / (16*TT);
        int rem = idx % (16*TT);
        int nl  = rem / TT;
        int t   = rem % TT;
        int n   = n0 + nl;
        if (n < NN)
            tile[nl*776 + c*TT + t] = x[((b*CC + c)*NN + n)*TT + t];
    }
    __syncthreads();
    for (int idx = threadIdx.x; idx < 16*CT; idx += 256) {
        int nl = idx / CT;
        int j  = idx % CT;
        int n  = n0 + nl;
        if (n < NN)
            xT[(size_t)(b*NN + n)*CT + j] = tile[nl*776 + j];
    }
}

// ---------------------------------------------------------------------------
// K2: Wh[bht][n][f] (bf16) = sum_c h[node][c,t] * W[h,c,f]; e1/e2 via p1/p2.
// ---------------------------------------------------------------------------
__global__ __launch_bounds__(256) void k2_wh_e(const float* __restrict__ hin,
                                               const float* __restrict__ W,
                                               const float* __restrict__ p1,
                                               const float* __restrict__ p2,
                                               __hip_bfloat16* __restrict__ Wh,
                                               float* __restrict__ e1,
                                               float* __restrict__ e2) {
    __shared__ float hL[4][CT];
    int wid  = threadIdx.x >> 6;
    int lane = threadIdx.x & 63;
    int gidx = blockIdx.x * 4 + wid;
    int b = gidx / NN, n = gidx % NN;

    {
        const float4* src = (const float4*)(hin + (size_t)gidx * CT);
        float4* dst = (float4*)hL[wid];
        for (int i = lane; i < CT/4; i += 64) dst[i] = src[i];
    }
    __syncthreads();

    const float*  hLw = hL[wid];
    const float4* h4  = (const float4*)hLw;
    int h  = lane >> 4;
    int fb = lane & 15;

    float acc[4][TT];
    #pragma unroll
    for (int q = 0; q < 4; ++q)
        #pragma unroll
        for (int t = 0; t < TT; ++t) acc[q][t] = 0.f;

    for (int c = 0; c < CC; ++c) {
        float4 v0 = h4[c*3+0], v1 = h4[c*3+1], v2 = h4[c*3+2];
        float hv[12] = {v0.x,v0.y,v0.z,v0.w, v1.x,v1.y,v1.z,v1.w,
                        v2.x,v2.y,v2.z,v2.w};
        const float* Wc = W + (h*CC + c)*FF + fb;
        float w0 = Wc[0], w1 = Wc[16], w2 = Wc[32], w3 = Wc[48];
        #pragma unroll
        for (int t = 0; t < TT; ++t) {
            acc[0][t] += hv[t]*w0;
            acc[1][t] += hv[t]*w1;
            acc[2][t] += hv[t]*w2;
            acc[3][t] += hv[t]*w3;
        }
    }
    #pragma unroll
    for (int q = 0; q < 4; ++q) {
        int f = fb + 16*q;
        #pragma unroll
        for (int t = 0; t < TT; ++t) {
            Wh[((size_t)((b*HH + h)*TT + t)*NN + n)*FF + f] =
                __float2bfloat16(acc[q][t]);
        }
    }

    int t2 = lane & 15;
    if (t2 < TT) {
        int h2 = lane >> 4;
        float s1 = 0.f, s2 = 0.f;
        for (int c = 0; c < CC; ++c) {
            float v = hLw[c*TT + t2];
            s1 += v * p1[h2*CC + c];
            s2 += v * p2[h2*CC + c];
        }
        int idx = ((b*HH + h2)*TT + t2)*NN + n;
        e1[idx] = s1;
        e2[idx] = s2;
    }
}

// ---------------------------------------------------------------------------
// K2T: Wh[bht][n<500][64] -> WhT[bht][f=64][m=512] bf16, m>=500 zeroed.
// Split by f-half: block = (bht, fh).  32 KB LDS -> 4 blocks/CU, 768 blocks.
// ---------------------------------------------------------------------------
__global__ __launch_bounds__(256) void k2t(const ushort_t* __restrict__ Wh,
                                           ushort_t* __restrict__ WhT) {
    __shared__ ushort_t tile[32*512];     // 32 KB
    int wid  = threadIdx.x >> 6;
    int lane = threadIdx.x & 63;
    int bht  = blockIdx.x >> 1;
    int fh   = blockIdx.x & 1;            // f half: f0 = fh*32
    const ushort_t* src = Wh + (size_t)bht * NN * FF + fh*32;

    for (int task = wid; task < 32; task += 4) {
        int i  = task >> 2;               // m-block of 64 (0..7)
        int fo = task & 3;                // f-octet within half (0..3)
        int m  = i*64 + lane;
        short8 v = {0,0,0,0,0,0,0,0};
        if (m < NN) v = *(const short8*)(src + m*FF + fo*8);
        #pragma unroll
        for (int j = 0; j < 8; ++j)
            tile[(fo*8 + j)*512 + m] = (ushort_t)v[j];
    }
    __syncthreads();

    ushort_t* dst = WhT + (size_t)bht * 64 * 512 + (size_t)fh*32*512;
    for (int f = wid; f < 32; f += 4) {
        short8 v = *(const short8*)&tile[f*512 + lane*8];
        *(short8*)(dst + f*512 + lane*8) = v;
    }
}

// ---------------------------------------------------------------------------
// K3: attention PV via MFMA, register-built dense A, separable exp:
//   exp(lrelu(e1+e2)) = s>0 ? exp2(e1s)*P2[m] : exp2(.2*e1s)*N2[m]
// with P2 = exp2(e2s), N2 = exp2(.2*e2s) precomputed per-m in LDS (no exp2
// in the inner loop).  Sign test: P2[m] > 1/p1row (boundary-safe: both
// branches agree at s~0).  Mask folded as f32 multiplier (maskF table).
// Pack via v_cvt_pk_bf16_f32.  Row-sum via all-ones B frag.
// ---------------------------------------------------------------------------
__global__ __launch_bounds__(256, 4) void k3_attn(const ushort_t* __restrict__ WhT,
                                                  const float* __restrict__ e1,
                                                  const float* __restrict__ e2,
                                                  const float* __restrict__ maskF,
                                                  ushort_t* __restrict__ hprB) {
    __shared__ float P2s[512], N2s[512];
    int tid  = threadIdx.x;
    int wid  = tid >> 6;
    int lane = tid & 63;
    int bht  = blockIdx.x >> 2;
    int rb   = blockIdx.x & 3;
    int b    = bht / NBT;
    int ht   = bht % NBT;

    const float* e1p = e1 + (size_t)bht * NN;
    const float* e2p = e2 + (size_t)bht * NN;
    const ushort_t* WT = WhT + (size_t)bht * 64 * 512;
    const float L2E = 1.4426950408889634f;

    for (int i = tid; i < 512; i += 256) {
        float e = (i < NN) ? e2p[i] * L2E : 0.f;
        P2s[i] = __builtin_amdgcn_exp2f(e);
        N2s[i] = __builtin_amdgcn_exp2f(0.2f * e);
    }
    __syncthreads();

    int quad = lane >> 4;                 // 0..3
    int r    = lane & 15;                 // A-row / B-col / C-col

    const short8 ONES = {0x3F80,0x3F80,0x3F80,0x3F80,
                         0x3F80,0x3F80,0x3F80,0x3F80}; // bf16 1.0 x8

    int n0a = rb*128 + wid*32;
    int n0b = n0a + 16;
    int na = n0a + r, nb = n0b + r;
    float e1a = ((na < NN) ? e1p[na] : 0.f) * L2E;
    float e1b = ((nb < NN) ? e1p[nb] : 0.f) * L2E;
    float p1a = __builtin_amdgcn_exp2f(e1a);
    float n1a = __builtin_amdgcn_exp2f(0.2f * e1a);
    float p1b = __builtin_amdgcn_exp2f(e1b);
    float n1b = __builtin_amdgcn_exp2f(0.2f * e1b);
    float ra  = 1.0f / p1a;
    float rb_ = 1.0f / p1b;
    const float* mfa = maskF + (size_t)na * 512;
    const float* mfb = maskF + (size_t)nb * 512;

    floatx4 Ca[4], Cb[4];
    floatx4 Csa = {0.f,0.f,0.f,0.f}, Csb = {0.f,0.f,0.f,0.f};
    #pragma unroll
    for (int ft = 0; ft < 4; ++ft) {
        Ca[ft] = (floatx4){0.f,0.f,0.f,0.f};
        Cb[ft] = (floatx4){0.f,0.f,0.f,0.f};
    }

    #pragma unroll 2
    for (int ki = 0; ki < 16; ++ki) {
        int kb = ki*32 + quad*8;

        short8 bfr[4];
        #pragma unroll
        for (int ft = 0; ft < 4; ++ft)
            bfr[ft] = *(const short8*)(WT + (size_t)(ft*16 + r)*512 + kb);

        float4 p2lo = *(const float4*)&P2s[kb];
        float4 p2hi = *(const float4*)&P2s[kb + 4];
        float4 n2lo = *(const float4*)&N2s[kb];
        float4 n2hi = *(const float4*)&N2s[kb + 4];
        float pv[8] = {p2lo.x,p2lo.y,p2lo.z,p2lo.w, p2hi.x,p2hi.y,p2hi.z,p2hi.w};
        float nv[8] = {n2lo.x,n2lo.y,n2lo.z,n2lo.w, n2hi.x,n2hi.y,n2hi.z,n2hi.w};

        // ---- tile a ----
        {
            float4 m0 = *(const float4*)&mfa[kb];
            float4 m1 = *(const float4*)&mfa[kb + 4];
            float mv[8] = {m0.x,m0.y,m0.z,m0.w, m1.x,m1.y,m1.z,m1.w};
            union { uint_t u[4]; short8 s; } av;
            #pragma unroll
            for (int p = 0; p < 4; ++p) {
                float E0 = ((pv[2*p]   > ra) ? pv[2*p]*p1a   : nv[2*p]*n1a)   * mv[2*p];
                float E1 = ((pv[2*p+1] > ra) ? pv[2*p+1]*p1a : nv[2*p+1]*n1a) * mv[2*p+1];
                av.u[p] = pkbf(E0, E1);
            }
            #pragma unroll
            for (int ft = 0; ft < 4; ++ft)
                Ca[ft] = __builtin_amdgcn_mfma_f32_16x16x32_bf16(av.s, bfr[ft], Ca[ft], 0, 0, 0);
            Csa = __builtin_amdgcn_mfma_f32_16x16x32_bf16(av.s, ONES, Csa, 0, 0, 0);
        }
        // ---- tile b ----
        {
            float4 m0 = *(const float4*)&mfb[kb];
            float4 m1 = *(const float4*)&mfb[kb + 4];
            float mv[8] = {m0.x,m0.y,m0.z,m0.w, m1.x,m1.y,m1.z,m1.w};
            union { uint_t u[4]; short8 s; } av;
            #pragma unroll
            for (int p = 0; p < 4; ++p) {
                float E0 = ((pv[2*p]   > rb_) ? pv[2*p]*p1b   : nv[2*p]*n1b)   * mv[2*p];
                float E1 = ((pv[2*p+1] > rb_) ? pv[2*p+1]*p1b : nv[2*p+1]*n1b) * mv[2*p+1];
                av.u[p] = pkbf(E0, E1);
            }
            #pragma unroll
            for (int ft = 0; ft < 4; ++ft)
                Cb[ft] = __builtin_amdgcn_mfma_f32_16x16x32_bf16(av.s, bfr[ft], Cb[ft], 0, 0, 0);
            Csb = __builtin_amdgcn_mfma_f32_16x16x32_bf16(av.s, ONES, Csb, 0, 0, 0);
        }
    }

    // epilogue: scale by 1/lsum, ELU, store bf16 node-major
    #pragma unroll
    for (int reg = 0; reg < 4; ++reg) {
        int row = quad*4 + reg;
        int n = n0a + row;
        if (n < NN) {
            float inv = 1.0f / Csa[reg];
            size_t base = ((size_t)(b*NN + n)*NBT + ht)*FF;
            #pragma unroll
            for (int ft = 0; ft < 4; ++ft) {
                float v = Ca[ft][reg] * inv;
                v = v > 0.f ? v : __expf(v) - 1.f;
                hprB[base + ft*16 + r] = f2bf(v);
            }
        }
        n = n0b + row;
        if (n < NN) {
            float inv = 1.0f / Csb[reg];
            size_t base = ((size_t)(b*NN + n)*NBT + ht)*FF;
            #pragma unroll
            for (int ft = 0; ft < 4; ++ft) {
                float v = Cb[ft][reg] * inv;
                v = v > 0.f ? v : __expf(v) - 1.f;
                hprB[base + ft*16 + r] = f2bf(v);
            }
        }
    }
}

// ---------------------------------------------------------------------------
// K4: head-mix 1x1 conv + residual via MFMA.  1 node per WAVE, 1000 blocks.
// ---------------------------------------------------------------------------
__global__ __launch_bounds__(256) void k4_mfma(const ushort_t* __restrict__ hprB,
                                               const ushort_t* __restrict__ WgB,
                                               const float* __restrict__ bg,
                                               const float* __restrict__ xT,
                                               float* __restrict__ hnext) {
    int wid  = threadIdx.x >> 6;
    int lane = threadIdx.x & 63;
    int quad = lane >> 4;
    int r    = lane & 15;

    short8 Afr[4][8];
    #pragma unroll
    for (int ot = 0; ot < 4; ++ot)
        #pragma unroll
        for (int kc = 0; kc < 8; ++kc)
            Afr[ot][kc] = *(const short8*)(WgB + (size_t)(ot*16 + r)*HF + kc*32 + quad*8);

    float4 bgv[4];
    #pragma unroll
    for (int ot = 0; ot < 4; ++ot)
        bgv[ot] = *(const float4*)(bg + ot*16 + quad*4);

    int tcl = r < TT ? r : TT-1;

    int node = blockIdx.x*4 + wid;
    const ushort_t* P = hprB + (size_t)node * (NBT*FF);

    floatx4 C[4];
    #pragma unroll
    for (int ot = 0; ot < 4; ++ot) C[ot] = (floatx4){0.f,0.f,0.f,0.f};

    #pragma unroll
    for (int kc = 0; kc < 8; ++kc) {
        int k = kc*32 + quad*8;
        int h = k >> 6, f0 = k & 63;
        short8 bfr = *(const short8*)(P + (h*TT + tcl)*FF + f0);
        #pragma unroll
        for (int ot = 0; ot < 4; ++ot)
            C[ot] = __builtin_amdgcn_mfma_f32_16x16x32_bf16(Afr[ot][kc], bfr, C[ot], 0, 0, 0);
    }

    if (r < TT) {
        float* hout = hnext + (size_t)node * CT;
        const float* xp = xT + (size_t)node * CT;
        #pragma unroll
        for (int ot = 0; ot < 4; ++ot) {
            #pragma unroll
            for (int reg = 0; reg < 4; ++reg) {
                int o = ot*16 + quad*4 + reg;
                float v = C[ot][reg] + bgv[ot][reg];
                hout[o*TT + r] = 0.05f*xp[o*TT + r] + 0.95f*v;
            }
        }
    }
}

// ---------------------------------------------------------------------------
// K45: fused layer-2 head-mix + final mix.  1 node per WAVE, 1000 blocks.
// h2 never hits global: computed via MFMA (k4 body), staged to wave-private
// LDS, consumed by the k5 VALU mix.  No __syncthreads (all LDS per-wave).
// ---------------------------------------------------------------------------
__global__ __launch_bounds__(256) void k45_fused(const ushort_t* __restrict__ hprB,
                                                 const ushort_t* __restrict__ WgB,
                                                 const float* __restrict__ bg,
                                                 const float* __restrict__ xT,
                                                 const float* __restrict__ h1,
                                                 const float* __restrict__ WmT,
                                                 const float* __restrict__ bm,
                                                 float* __restrict__ out) {
    __shared__ float S[4][3][CT];         // 36864 B: [wid][x|h1|h2]
    int wid  = threadIdx.x >> 6;
    int lane = threadIdx.x & 63;
    int quad = lane >> 4;
    int r    = lane & 15;

    int node = blockIdx.x*4 + wid;
    int b = node / NN, n = node % NN;

    {   // stage x, h1 (coalesced, wave-private)
        const float4* sx = (const float4*)(xT + (size_t)node*CT);
        const float4* sh = (const float4*)(h1 + (size_t)node*CT);
        float4* d0 = (float4*)S[wid][0];
        float4* d1 = (float4*)S[wid][1];
        for (int i = lane; i < CT/4; i += 64) { d0[i] = sx[i]; d1[i] = sh[i]; }
    }

    // ---- k4 body: h2 = 0.05x + 0.95(Wg @ hpr + bg) ----
    short8 Afr[4][8];
    #pragma unroll
    for (int ot = 0; ot < 4; ++ot)
        #pragma unroll
        for (int kc = 0; kc < 8; ++kc)
            Afr[ot][kc] = *(const short8*)(WgB + (size_t)(ot*16 + r)*HF + kc*32 + quad*8);
    float4 bgv[4];
    #pragma unroll
    for (int ot = 0; ot < 4; ++ot)
        bgv[ot] = *(const float4*)(bg + ot*16 + quad*4);

    int tcl = r < TT ? r : TT-1;
    const ushort_t* P = hprB + (size_t)node * (NBT*FF);

    floatx4 C[4];
    #pragma unroll
    for (int ot = 0; ot < 4; ++ot) C[ot] = (floatx4){0.f,0.f,0.f,0.f};
    #pragma unroll
    for (int kc = 0; kc < 8; ++kc) {
        int k = kc*32 + quad*8;
        int h = k >> 6, f0 = k & 63;
        short8 bfr = *(const short8*)(P + (h*TT + tcl)*FF + f0);
        #pragma unroll
        for (int ot = 0; ot < 4; ++ot)
            C[ot] = __builtin_amdgcn_mfma_f32_16x16x32_bf16(Afr[ot][kc], bfr, C[ot], 0, 0, 0);
    }

    if (r < TT) {   // h2 -> wave-private LDS (compiler inserts lgkm waits)
        #pragma unroll
        for (int ot = 0; ot < 4; ++ot) {
            #pragma unroll
            for (int reg = 0; reg < 4; ++reg) {
                int o = ot*16 + quad*4 + reg;
                float v = C[ot][reg] + bgv[ot][reg];
                S[wid][2][o*TT + r] = 0.05f*S[wid][0][o*TT + r] + 0.95f*v;
            }
        }
    }

    // ---- k5 body: out = bm + Wm @ [x|h1|h2] ----
    float (*Sw)[CT] = S[wid];
    int ob = lane & 15;
    int tq = lane >> 4;

    float acc[4][3];
    #pragma unroll
    for (int oi = 0; oi < 4; ++oi) {
        float bv = bm[ob + 16*oi];
        #pragma unroll
        for (int ti = 0; ti < 3; ++ti) acc[oi][ti] = bv;
    }

    for (int c = 0; c < CC; ++c) {
        float v0[3], v1[3], v2[3];
        #pragma unroll
        for (int ti = 0; ti < 3; ++ti) {
            int t = tq + 4*ti;
            v0[ti] = Sw[0][c*TT + t];
            v1[ti] = Sw[1][c*TT + t];
            v2[ti] = Sw[2][c*TT + t];
        }
        #pragma unroll
        for (int oi = 0; oi < 4; ++oi) {
            int o = ob + 16*oi;
            float w0 = WmT[(c       )*64 + o];
            float w1 = WmT[(CC  + c )*64 + o];
            float w2 = WmT[(2*CC + c)*64 + o];
            #pragma unroll
            for (int ti = 0; ti < 3; ++ti) {
                acc[oi][ti] += v0[ti]*w0 + v1[ti]*w1 + v2[ti]*w2;
            }
        }
    }

    #pragma unroll
    for (int oi = 0; oi < 4; ++oi) {
        int o = ob + 16*oi;
        #pragma unroll
        for (int ti = 0; ti < 3; ++ti) {
            int t = tq + 4*ti;
            out[((b*CC + o)*NN + n)*TT + t] = acc[oi][ti];
        }
    }
}

// ---------------------------------------------------------------------------
extern "C" void kernel_launch(void* const* d_in, const int* in_sizes, int n_in,
                              void* d_out, int out_size, void* d_ws, size_t ws_size,
                              hipStream_t stream) {
    const float* x   = (const float*)d_in[0];
    const float* adj = (const float*)d_in[1];
    const float* W   = (const float*)d_in[2];
    const float* a1  = (const float*)d_in[3];
    const float* a2  = (const float*)d_in[4];
    const float* Wg  = (const float*)d_in[5];
    const float* bg  = (const float*)d_in[6];
    const float* Wm  = (const float*)d_in[7];
    const float* bm  = (const float*)d_in[8];
    float* out = (float*)d_out;

    char* ws = (char*)d_ws;
    size_t off = 0;
    auto alloc = [&](size_t bytes) -> void* {
        void* p = ws + off;
        off += (bytes + 255) & ~(size_t)255;
        return p;
    };

    float* maskF = (float*)alloc((size_t)512 * 512 * 4);                    // 1 MB
    float* p1   = (float*)alloc(HH*CC * sizeof(float));
    float* p2   = (float*)alloc(HH*CC * sizeof(float));
    float* WmT  = (float*)alloc(3*CC*CC * sizeof(float));
    ushort_t* WgB = (ushort_t*)alloc((size_t)FF*HF * 2);
    float* xT   = (float*)alloc((size_t)NNODE * CT * sizeof(float));        // 12.3 MB
    ushort_t* Wh   = (ushort_t*)alloc((size_t)NROWS * FF * 2);              // 24.6 MB
    ushort_t* WhT  = (ushort_t*)alloc((size_t)NBHT * 64 * 512 * 2);         // 25.2 MB
    ushort_t* hprB = (ushort_t*)alloc((size_t)NNODE * NBT * FF * 2);        // 24.6 MB
    float* e1   = (float*)alloc((size_t)NROWS * sizeof(float));
    float* e2   = (float*)alloc((size_t)NROWS * sizeof(float));
    float* h1   = (float*)alloc((size_t)NNODE * CT * sizeof(float));        // 12.3 MB
    (void)ws_size;

    k01_setup<<<1138, 256, 0, stream>>>(adj, W, a1, a2, Wm, Wg,
                                        maskF, p1, p2, WmT, WgB);
    k6_xt    <<<256,  256, 0, stream>>>(x, xT);

    // layer 1
    k2_wh_e <<<NNODE/4, 256, 0, stream>>>(xT, W, p1, p2, (__hip_bfloat16*)Wh, e1, e2);
    k2t     <<<NBHT*2,  256, 0, stream>>>(Wh, WhT);
    k3_attn <<<NBHT*4,  256, 0, stream>>>(WhT, e1, e2, maskF, hprB);
    k4_mfma <<<NNODE/4, 256, 0, stream>>>(hprB, WgB, bg, xT, h1);

    // layer 2
    k2_wh_e <<<NNODE/4, 256, 0, stream>>>(h1, W, p1, p2, (__hip_bfloat16*)Wh, e1, e2);
    k2t     <<<NBHT*2,  256, 0, stream>>>(Wh, WhT);
    k3_attn <<<NBHT*4,  256, 0, stream>>>(WhT, e1, e2, maskF, hprB);

    // fused layer-2 mix + final
    k45_fused<<<NNODE/4, 256, 0, stream>>>(hprB, WgB, bg, xT, h1, WmT, bm, out);
}